// Round 4
// baseline (8332.694 us; speedup 1.0000x reference)
//
#include <hip/hip_runtime.h>
#include <cstdint>

typedef _Float16 half_t;
typedef __attribute__((ext_vector_type(2))) _Float16 half2_t;
typedef __attribute__((ext_vector_type(4))) _Float16 half4_t;
typedef __attribute__((ext_vector_type(8))) _Float16 half8_t;
typedef __attribute__((ext_vector_type(4))) float f32x4;

#define B_    32
#define DIN   128
#define LEN   2048
#define DS    512
#define NKT   16                            // K-tiles of 32 (16x16x32 MFMA)

// ---- stream variant (preferred): 10 kt in AGPRs, 6 kt streamed from L2
#define KTR_S 10
#define KTL_G (NKT - KTR_S)                 // 6 streamed tiles
#define W16_BYTES (KTL_G * 32 * 1024)       // 196608 B staging

// ---- LDS fallback variant (round-3): 12 kt regs, 4 kt LDS
#define KTR_F 12
#define KTL_F (NKT - KTR_F)
#define LDSB_BYTES (KTL_F * 32 * 1024)
#define HBUF_OFF   LDSB_BYTES
#define LDSF_BYTES (LDSB_BYTES + 2 * DS * 2)

__device__ __forceinline__ float fast_tanh(float x) {
    float e = __expf(2.0f * x);
    return 1.0f - 2.0f / (e + 1.0f);
}

__device__ __forceinline__ float fd2(uint32_t a, uint32_t b, float c) {
    return __builtin_amdgcn_fdot2(__builtin_bit_cast(half2_t, a),
                                  __builtin_bit_cast(half2_t, b), c, false);
}

// B-fragment for 16x16x32: lane(c=lane&15, q=lane>>4) holds B[k0+q*8+j][n0+c]
// = W[n0+c][k0+q*8+j], j=0..7 -> 8 consecutive f32 from W row n0+c.
__device__ __forceinline__ half8_t load_wfrag(const float* __restrict__ W,
                                              int n0, int c, int q, int kt) {
    const float* p = W + (size_t)(n0 + c) * DS + kt * 32 + q * 8;
    float4 f0 = *(const float4*)p;
    float4 f1 = *(const float4*)(p + 4);
    half8_t r = {(half_t)f0.x, (half_t)f0.y, (half_t)f0.z, (half_t)f0.w,
                 (half_t)f1.x, (half_t)f1.y, (half_t)f1.z, (half_t)f1.w};
    return r;
}

// ---------------------------------------------------------------- kernel W16
// Build f16 B-fragment staging for streamed tiles: frag f=(kt-KTR_S)*32+gid,
// 1 KB each, lane-linear so the scan's loads are coalesced b128.
__global__ __launch_bounds__(64) void rnn_w16_kernel(
    const float* __restrict__ Whh, half_t* __restrict__ W16)
{
    const int f    = blockIdx.x;             // 0 .. KTL_G*32-1
    const int kt   = KTR_S + (f >> 5);
    const int gid  = f & 31;
    const int lane = threadIdx.x;
    const int c    = lane & 15;
    const int q    = lane >> 4;
    half8_t w = load_wfrag(Whh, gid * 16, c, q, kt);
    *(half8_t*)(W16 + (size_t)f * 512 + lane * 8) = w;
}

// ---------------------------------------------------------------- kernel A
// pre[b][l][h] = sum_d x[b][d][l]*W_ih[h][d] + b_ih[h] + b_hh[h]   (f16 out)
__global__ __launch_bounds__(256) void rnn_pre_kernel(
    const float* __restrict__ x, const float* __restrict__ Wih,
    const float* __restrict__ bih, const float* __restrict__ bhh,
    half_t* __restrict__ pre)
{
    __shared__ half_t Xs[64 * 136];
    __shared__ half_t Ws[128 * 136];
    const int t  = threadIdx.x;
    const int l0 = blockIdx.x * 64;
    const int b  = blockIdx.y;
    const int h0 = blockIdx.z * 128;

#pragma unroll
    for (int i = 0; i < 32; ++i) {
        int idx = i * 256 + t;
        int j = idx & 63, d = idx >> 6;
        Xs[j * 136 + d] = (half_t)x[(size_t)b * DIN * LEN + (size_t)d * LEN + l0 + j];
    }
#pragma unroll
    for (int i = 0; i < 16; ++i) {
        int f4 = i * 256 + t;
        int h = f4 >> 5, d4 = f4 & 31;
        float4 w = *(const float4*)&Wih[(size_t)(h0 + h) * DIN + d4 * 4];
        half4_t hw = {(half_t)w.x, (half_t)w.y, (half_t)w.z, (half_t)w.w};
        *(half4_t*)&Ws[h * 136 + d4 * 4] = hw;
    }
    __syncthreads();

    const int lb = (t >> 4) * 4;
    const int hb = (t & 15) * 8;
    float acc[4][8];
#pragma unroll
    for (int i = 0; i < 4; ++i)
#pragma unroll
        for (int j = 0; j < 8; ++j) acc[i][j] = 0.f;

    for (int kc = 0; kc < DIN; kc += 8) {
        uint4 xa[4], wb[8];
#pragma unroll
        for (int i = 0; i < 4; ++i) xa[i] = *(const uint4*)&Xs[(lb + i) * 136 + kc];
#pragma unroll
        for (int j = 0; j < 8; ++j) wb[j] = *(const uint4*)&Ws[(hb + j) * 136 + kc];
#pragma unroll
        for (int i = 0; i < 4; ++i)
#pragma unroll
            for (int j = 0; j < 8; ++j) {
                float a = acc[i][j];
                a = fd2(xa[i].x, wb[j].x, a);
                a = fd2(xa[i].y, wb[j].y, a);
                a = fd2(xa[i].z, wb[j].z, a);
                a = fd2(xa[i].w, wb[j].w, a);
                acc[i][j] = a;
            }
    }

    float bias[8];
#pragma unroll
    for (int j = 0; j < 8; ++j) bias[j] = bih[h0 + hb + j] + bhh[h0 + hb + j];
#pragma unroll
    for (int i = 0; i < 4; ++i) {
        half8_t s;
#pragma unroll
        for (int j = 0; j < 8; ++j) s[j] = (half_t)(acc[i][j] + bias[j]);
        *(half8_t*)&pre[((size_t)b * LEN + l0 + lb + i) * DS + h0 + hb] = s;
    }
}

// ---------------------------------------------------------------- kernel B (stream)
// One block per batch. Wave w owns n in [w*64, w*64+64) as 4 N-tiles.
// kt 0..9 B-frags in AGPRs; kt 10..15 streamed from W16 (L2-hot, coalesced
// b128, rolling 2-tile pipeline). LDS holds only the h ping-pong (2 KB).
__global__ __launch_bounds__(512) __attribute__((amdgpu_waves_per_eu(2, 2)))
void rnn_recur_stream(
    const float* __restrict__ Whh, const half_t* __restrict__ W16,
    const half_t* __restrict__ pre, half_t* __restrict__ hs)
{
    __shared__ half_t hbuf[2][DS];
    const int t    = threadIdx.x;
    const int b    = blockIdx.x;
    const int w    = t >> 6;
    const int lane = t & 63;
    const int c    = lane & 15;
    const int q    = lane >> 4;
    const int n0w  = w * 64;

    // AGPR-resident B-fragments (40 x half8 = 160 regs)
    half8_t breg[KTR_S][4];
#pragma unroll
    for (int kt = 0; kt < KTR_S; ++kt)
#pragma unroll
        for (int nt = 0; nt < 4; ++nt)
            breg[kt][nt] = load_wfrag(Whh, n0w + nt * 16, c, q, kt);

    if (t < DS) hbuf[0][t] = (half_t)0.f;    // h_{-1} = 0
    __syncthreads();

    // streamed-frag base: frag f = (kt-KTR_S)*32 + w*4 + nt, 64 uint4 each
    const uint4* W16v = (const uint4*)W16 + ((w * 4) << 6) + lane;
    const half_t* pp  = pre + (size_t)b * LEN * DS + n0w + c;   // q==0 lanes only
    half_t* hsb = hs + (size_t)b * DS;

    float pv_cur[4] = {0.f, 0.f, 0.f, 0.f};
    if (q == 0) {
#pragma unroll
        for (int nt = 0; nt < 4; ++nt) pv_cur[nt] = (float)pp[nt * 16];
    }

    int par = 0;
    for (int l = 0; l < LEN; ++l) {
        const int ln = (l + 1 < LEN) ? (l + 1) : (LEN - 1);
        float pv_nxt[4];
        if (q == 0) {
#pragma unroll
            for (int nt = 0; nt < 4; ++nt)
                pv_nxt[nt] = (float)pp[(size_t)ln * DS + nt * 16];
        }

        // kick off stream pipeline: tiles KTR_S, KTR_S+1
        uint4 sb[2][4];
#pragma unroll
        for (int j = 0; j < 2; ++j)
#pragma unroll
            for (int nt = 0; nt < 4; ++nt)
                sb[j][nt] = W16v[((j * 32 + nt) << 6)];

        const char* hbp = (const char*)hbuf[par];
        f32x4 acc[4];
#pragma unroll
        for (int nt = 0; nt < 4; ++nt) acc[nt] = (f32x4){0.f, 0.f, 0.f, 0.f};

#pragma unroll
        for (int kt = 0; kt < KTR_S; ++kt) {
            half8_t a = *(const half8_t*)(hbp + kt * 64 + q * 16);  // multicast
#pragma unroll
            for (int nt = 0; nt < 4; ++nt)
                acc[nt] = __builtin_amdgcn_mfma_f32_16x16x32_f16(a, breg[kt][nt], acc[nt], 0, 0, 0);
        }
#pragma unroll
        for (int kt = KTR_S; kt < NKT; ++kt) {
            const int j = (kt - KTR_S) & 1;
            half8_t a = *(const half8_t*)(hbp + kt * 64 + q * 16);
#pragma unroll
            for (int nt = 0; nt < 4; ++nt)
                acc[nt] = __builtin_amdgcn_mfma_f32_16x16x32_f16(
                    a, __builtin_bit_cast(half8_t, sb[j][nt]), acc[nt], 0, 0, 0);
            if (kt + 2 < NKT) {                // refill (compile-time branch)
#pragma unroll
                for (int nt = 0; nt < 4; ++nt)
                    sb[j][nt] = W16v[(((kt + 2 - KTR_S) * 32 + nt) << 6)];
            }
        }

        if (q == 0) {  // C/D: col=lane&15, row=(lane>>4)*4+reg; m=0 -> q==0,.x
            half_t* hn = hbuf[par ^ 1];
            half_t* hrow = hsb + (size_t)l * (B_ * DS);
#pragma unroll
            for (int nt = 0; nt < 4; ++nt) {
                half_t hv = (half_t)fast_tanh(pv_cur[nt] + acc[nt].x);
                hn[n0w + nt * 16 + c] = hv;
                hrow[n0w + nt * 16 + c] = hv;
            }
        }
#pragma unroll
        for (int nt = 0; nt < 4; ++nt) pv_cur[nt] = pv_nxt[nt];
        par ^= 1;
        __syncthreads();
    }
}

// ---------------------------------------------------------------- kernel B (fallback, round-3)
__global__ __launch_bounds__(512) __attribute__((amdgpu_waves_per_eu(2, 2)))
void rnn_recur_lds(
    const float* __restrict__ Whh, const half_t* __restrict__ pre,
    half_t* __restrict__ hs)
{
    extern __shared__ char smem[];
    const int t    = threadIdx.x;
    const int b    = blockIdx.x;
    const int w    = t >> 6;
    const int lane = t & 63;
    const int c    = lane & 15;
    const int q    = lane >> 4;
    const int n0w  = w * 64;

    half8_t breg[KTR_F][4];
#pragma unroll
    for (int kt = 0; kt < KTR_F; ++kt)
#pragma unroll
        for (int nt = 0; nt < 4; ++nt)
            breg[kt][nt] = load_wfrag(Whh, n0w + nt * 16, c, q, kt);

#pragma unroll
    for (int kt = KTR_F; kt < NKT; ++kt)
#pragma unroll
        for (int nt = 0; nt < 4; ++nt) {
            half8_t f = load_wfrag(Whh, n0w + nt * 16, c, q, kt);
            int gid = w * 4 + nt;
            *(half8_t*)(smem + (((kt - KTR_F) * 32 + gid) << 10) + lane * 16) = f;
        }
    if (t < DS) *(half_t*)(smem + HBUF_OFF + t * 2) = (half_t)0.f;
    __syncthreads();

    const half_t* prew = pre + (size_t)b * LEN * DS + n0w + lane;
    half_t* hsb = hs + (size_t)b * DS;
    float pv_cur = (float)prew[0];

    int par = 0;
    for (int l = 0; l < LEN; ++l) {
        int lnx = (l + 1 < LEN) ? (l + 1) : (LEN - 1);
        float pv_nxt = (float)prew[(size_t)lnx * DS];

        const char* hb = smem + HBUF_OFF + par * 1024;
        f32x4 acc0 = {0.f,0.f,0.f,0.f}, acc1 = {0.f,0.f,0.f,0.f};
        f32x4 acc2 = {0.f,0.f,0.f,0.f}, acc3 = {0.f,0.f,0.f,0.f};
#pragma unroll
        for (int kt = 0; kt < KTR_F; ++kt) {
            half8_t a = *(const half8_t*)(hb + kt * 64 + q * 16);
            acc0 = __builtin_amdgcn_mfma_f32_16x16x32_f16(a, breg[kt][0], acc0, 0, 0, 0);
            acc1 = __builtin_amdgcn_mfma_f32_16x16x32_f16(a, breg[kt][1], acc1, 0, 0, 0);
            acc2 = __builtin_amdgcn_mfma_f32_16x16x32_f16(a, breg[kt][2], acc2, 0, 0, 0);
            acc3 = __builtin_amdgcn_mfma_f32_16x16x32_f16(a, breg[kt][3], acc3, 0, 0, 0);
        }
#pragma unroll
        for (int kt = KTR_F; kt < NKT; ++kt) {
            half8_t a = *(const half8_t*)(hb + kt * 64 + q * 16);
            const char* bb = smem + (((kt - KTR_F) * 32 + w * 4) << 10) + lane * 16;
            half8_t b0 = *(const half8_t*)(bb);
            half8_t b1 = *(const half8_t*)(bb + 1024);
            half8_t b2 = *(const half8_t*)(bb + 2048);
            half8_t b3 = *(const half8_t*)(bb + 3072);
            acc0 = __builtin_amdgcn_mfma_f32_16x16x32_f16(a, b0, acc0, 0, 0, 0);
            acc1 = __builtin_amdgcn_mfma_f32_16x16x32_f16(a, b1, acc1, 0, 0, 0);
            acc2 = __builtin_amdgcn_mfma_f32_16x16x32_f16(a, b2, acc2, 0, 0, 0);
            acc3 = __builtin_amdgcn_mfma_f32_16x16x32_f16(a, b3, acc3, 0, 0, 0);
        }

        float p0 = __shfl(pv_cur, c +  0, 64);
        float p1 = __shfl(pv_cur, c + 16, 64);
        float p2 = __shfl(pv_cur, c + 32, 64);
        float p3 = __shfl(pv_cur, c + 48, 64);

        if (q == 0) {
            half_t h0 = (half_t)fast_tanh(p0 + acc0.x);
            half_t h1 = (half_t)fast_tanh(p1 + acc1.x);
            half_t h2 = (half_t)fast_tanh(p2 + acc2.x);
            half_t h3 = (half_t)fast_tanh(p3 + acc3.x);
            char* hn = smem + HBUF_OFF + (par ^ 1) * 1024;
            *(half_t*)(hn + (n0w +  0 + c) * 2) = h0;
            *(half_t*)(hn + (n0w + 16 + c) * 2) = h1;
            *(half_t*)(hn + (n0w + 32 + c) * 2) = h2;
            *(half_t*)(hn + (n0w + 48 + c) * 2) = h3;
            half_t* hrow = hsb + (size_t)l * (B_ * DS);
            hrow[n0w +  0 + c] = h0;
            hrow[n0w + 16 + c] = h1;
            hrow[n0w + 32 + c] = h2;
            hrow[n0w + 48 + c] = h3;
        }
        pv_cur = pv_nxt;
        par ^= 1;
        __syncthreads();
    }
}

// ---------------------------------------------------------------- kernel C
__global__ __launch_bounds__(256) void rnn_out_kernel(
    const half_t* __restrict__ hs, const float* __restrict__ Wfc,
    const float* __restrict__ bfc, float* __restrict__ y)
{
    __shared__ half_t Hs[64 * 72];
    __shared__ half_t Ws[128 * 72];
    const int t  = threadIdx.x;
    const int r0 = blockIdx.x * 64;

    const int lb = (t >> 4) * 4;
    const int ob = (t & 15) * 8;
    float acc[4][8];
#pragma unroll
    for (int i = 0; i < 4; ++i)
#pragma unroll
        for (int j = 0; j < 8; ++j) acc[i][j] = 0.f;

    for (int kc = 0; kc < DS; kc += 64) {
#pragma unroll
        for (int i = 0; i < 2; ++i) {
            int u = i * 256 + t;
            int r = u >> 3, c8 = u & 7;
            uint4 v = ((const uint4*)(hs + (size_t)(r0 + r) * DS + kc))[c8];
            *(uint4*)&Hs[r * 72 + c8 * 8] = v;
        }
#pragma unroll
        for (int i = 0; i < 8; ++i) {
            int u = i * 256 + t;
            int o = u >> 4, c4 = u & 15;
            float4 wv = *(const float4*)&Wfc[(size_t)o * DS + kc + c4 * 4];
            half4_t hw = {(half_t)wv.x, (half_t)wv.y, (half_t)wv.z, (half_t)wv.w};
            *(half4_t*)&Ws[o * 72 + c4 * 4] = hw;
        }
        __syncthreads();
#pragma unroll
        for (int k8 = 0; k8 < 64; k8 += 8) {
            uint4 xa[4], wb[8];
#pragma unroll
            for (int i = 0; i < 4; ++i) xa[i] = *(const uint4*)&Hs[(lb + i) * 72 + k8];
#pragma unroll
            for (int j = 0; j < 8; ++j) wb[j] = *(const uint4*)&Ws[(ob + j) * 72 + k8];
#pragma unroll
            for (int i = 0; i < 4; ++i)
#pragma unroll
                for (int j = 0; j < 8; ++j) {
                    float a = acc[i][j];
                    a = fd2(xa[i].x, wb[j].x, a);
                    a = fd2(xa[i].y, wb[j].y, a);
                    a = fd2(xa[i].z, wb[j].z, a);
                    a = fd2(xa[i].w, wb[j].w, a);
                    acc[i][j] = a;
                }
        }
        __syncthreads();
    }

#pragma unroll
    for (int i = 0; i < 4; ++i) {
        float4 r0v = {fast_tanh(acc[i][0] + bfc[ob + 0]), fast_tanh(acc[i][1] + bfc[ob + 1]),
                      fast_tanh(acc[i][2] + bfc[ob + 2]), fast_tanh(acc[i][3] + bfc[ob + 3])};
        float4 r1v = {fast_tanh(acc[i][4] + bfc[ob + 4]), fast_tanh(acc[i][5] + bfc[ob + 5]),
                      fast_tanh(acc[i][6] + bfc[ob + 6]), fast_tanh(acc[i][7] + bfc[ob + 7])};
        float* yr = y + (size_t)(r0 + lb + i) * DIN + ob;
        *(float4*)yr       = r0v;
        *((float4*)yr + 1) = r1v;
    }
}

// ---------------------------------------------------------------- launch
extern "C" void kernel_launch(void* const* d_in, const int* in_sizes, int n_in,
                              void* d_out, int out_size, void* d_ws, size_t ws_size,
                              hipStream_t stream) {
    (void)in_sizes; (void)n_in; (void)out_size;
    const float* x   = (const float*)d_in[0];
    const float* Wih = (const float*)d_in[1];
    const float* Whh = (const float*)d_in[2];
    const float* bih = (const float*)d_in[3];
    const float* bhh = (const float*)d_in[4];
    const float* Wfc = (const float*)d_in[5];
    const float* bfc = (const float*)d_in[6];
    float* y = (float*)d_out;

    const size_t preB = (size_t)B_ * LEN * DS * 2;   // 64 MB
    const size_t hsB  = (size_t)B_ * LEN * DS * 2;   // 64 MB
    half_t* pre = (half_t*)d_ws;
    half_t* hs  = (half_t*)((char*)d_ws + preB);
    half_t* W16 = (half_t*)((char*)d_ws + preB + hsB);

    rnn_pre_kernel<<<dim3(LEN / 64, B_, DS / 128), 256, 0, stream>>>(x, Wih, bih, bhh, pre);

    if (ws_size >= preB + hsB + W16_BYTES) {
        rnn_w16_kernel<<<dim3(KTL_G * 32), 64, 0, stream>>>(Whh, W16);
        rnn_recur_stream<<<dim3(B_), 512, 0, stream>>>(Whh, W16, pre, hs);
    } else {
        hipFuncSetAttribute((const void*)rnn_recur_lds,
                            hipFuncAttributeMaxDynamicSharedMemorySize, LDSF_BYTES);
        rnn_recur_lds<<<dim3(B_), 512, LDSF_BYTES, stream>>>(Whh, pre, hs);
    }

    rnn_out_kernel<<<dim3(LEN * B_ / 64), 256, 0, stream>>>(hs, Wfc, bfc, y);
}

// Round 5
// 4909.056 us; speedup vs baseline: 1.6974x; 1.6974x over previous
//
#include <hip/hip_runtime.h>
#include <cstdint>

typedef _Float16 half_t;
typedef __attribute__((ext_vector_type(2))) _Float16 half2_t;
typedef __attribute__((ext_vector_type(4))) _Float16 half4_t;
typedef __attribute__((ext_vector_type(8))) _Float16 half8_t;
typedef __attribute__((ext_vector_type(4))) float f32x4;

#define B_    32
#define DIN   128
#define LEN   2048
#define DS    512
#define NKT   16                            // K-tiles of 32 (16x16x32 MFMA)
#define KTR   13                            // K-tiles resident in regs/AGPRs (208 regs)
#define KTL   (NKT - KTR)                   // 3 K-tiles streamed from LDS
#define LDSB_BYTES (KTL * 32 * 1024)        // 98304
#define HBUF_OFF   LDSB_BYTES
#define LDS_BYTES  (LDSB_BYTES + 2 * DS * 2)   // 100352 < 160 KiB

__device__ __forceinline__ float fast_tanh(float x) {
    float e = __expf(2.0f * x);        // large |x| saturates correctly via inf/0
    return 1.0f - 2.0f / (e + 1.0f);
}

__device__ __forceinline__ float fd2(uint32_t a, uint32_t b, float c) {
    return __builtin_amdgcn_fdot2(__builtin_bit_cast(half2_t, a),
                                  __builtin_bit_cast(half2_t, b), c, false);
}

// B-fragment for 16x16x32: lane(c=lane&15, q=lane>>4) holds B[k0+q*8+j][n0+c]
// = W[n0+c][k0+q*8+j], j=0..7 -> 8 consecutive f32 from W row n0+c.
__device__ __forceinline__ half8_t load_wfrag(const float* __restrict__ W,
                                              int n0, int c, int q, int kt) {
    const float* p = W + (size_t)(n0 + c) * DS + kt * 32 + q * 8;
    float4 f0 = *(const float4*)p;
    float4 f1 = *(const float4*)(p + 4);
    half8_t r = {(half_t)f0.x, (half_t)f0.y, (half_t)f0.z, (half_t)f0.w,
                 (half_t)f1.x, (half_t)f1.y, (half_t)f1.z, (half_t)f1.w};
    return r;
}

// ---------------------------------------------------------------- kernel A
// pre[b][l][h] = sum_d x[b][d][l]*W_ih[h][d] + b_ih[h] + b_hh[h]   (f16 out)
__global__ __launch_bounds__(256) void rnn_pre_kernel(
    const float* __restrict__ x, const float* __restrict__ Wih,
    const float* __restrict__ bih, const float* __restrict__ bhh,
    half_t* __restrict__ pre)
{
    __shared__ half_t Xs[64 * 136];
    __shared__ half_t Ws[128 * 136];
    const int t  = threadIdx.x;
    const int l0 = blockIdx.x * 64;
    const int b  = blockIdx.y;
    const int h0 = blockIdx.z * 128;

#pragma unroll
    for (int i = 0; i < 32; ++i) {
        int idx = i * 256 + t;
        int j = idx & 63, d = idx >> 6;
        Xs[j * 136 + d] = (half_t)x[(size_t)b * DIN * LEN + (size_t)d * LEN + l0 + j];
    }
#pragma unroll
    for (int i = 0; i < 16; ++i) {
        int f4 = i * 256 + t;
        int h = f4 >> 5, d4 = f4 & 31;
        float4 w = *(const float4*)&Wih[(size_t)(h0 + h) * DIN + d4 * 4];
        half4_t hw = {(half_t)w.x, (half_t)w.y, (half_t)w.z, (half_t)w.w};
        *(half4_t*)&Ws[h * 136 + d4 * 4] = hw;
    }
    __syncthreads();

    const int lb = (t >> 4) * 4;
    const int hb = (t & 15) * 8;
    float acc[4][8];
#pragma unroll
    for (int i = 0; i < 4; ++i)
#pragma unroll
        for (int j = 0; j < 8; ++j) acc[i][j] = 0.f;

    for (int kc = 0; kc < DIN; kc += 8) {
        uint4 xa[4], wb[8];
#pragma unroll
        for (int i = 0; i < 4; ++i) xa[i] = *(const uint4*)&Xs[(lb + i) * 136 + kc];
#pragma unroll
        for (int j = 0; j < 8; ++j) wb[j] = *(const uint4*)&Ws[(hb + j) * 136 + kc];
#pragma unroll
        for (int i = 0; i < 4; ++i)
#pragma unroll
            for (int j = 0; j < 8; ++j) {
                float a = acc[i][j];
                a = fd2(xa[i].x, wb[j].x, a);
                a = fd2(xa[i].y, wb[j].y, a);
                a = fd2(xa[i].z, wb[j].z, a);
                a = fd2(xa[i].w, wb[j].w, a);
                acc[i][j] = a;
            }
    }

    float bias[8];
#pragma unroll
    for (int j = 0; j < 8; ++j) bias[j] = bih[h0 + hb + j] + bhh[h0 + hb + j];
#pragma unroll
    for (int i = 0; i < 4; ++i) {
        half8_t s;
#pragma unroll
        for (int j = 0; j < 8; ++j) s[j] = (half_t)(acc[i][j] + bias[j]);
        *(half8_t*)&pre[((size_t)b * LEN + l0 + lb + i) * DS + h0 + hb] = s;
    }
}

// ---------------------------------------------------------------- kernel B
// MFMA scan: one block per batch. Wave w owns outputs n in [w*64, w*64+64)
// as 4 16-wide N-tiles. kt 0..12 B-frags in regs/AGPRs; kt 13..15 from LDS.
// pre values loaded directly by q==0 lanes (no shfl -> no ds_bpermute).
__global__ __launch_bounds__(512) __attribute__((amdgpu_waves_per_eu(2, 2)))
void rnn_recur_kernel(
    const float* __restrict__ Whh, const half_t* __restrict__ pre,
    half_t* __restrict__ hs)
{
    extern __shared__ char smem[];
    const int t    = threadIdx.x;
    const int b    = blockIdx.x;
    const int w    = t >> 6;
    const int lane = t & 63;
    const int c    = lane & 15;
    const int q    = lane >> 4;
    const int n0w  = w * 64;

    half8_t breg[KTR][4];
#pragma unroll
    for (int kt = 0; kt < KTR; ++kt)
#pragma unroll
        for (int nt = 0; nt < 4; ++nt)
            breg[kt][nt] = load_wfrag(Whh, n0w + nt * 16, c, q, kt);

#pragma unroll
    for (int kt = KTR; kt < NKT; ++kt)
#pragma unroll
        for (int nt = 0; nt < 4; ++nt) {
            half8_t f = load_wfrag(Whh, n0w + nt * 16, c, q, kt);
            int gid = w * 4 + nt;
            *(half8_t*)(smem + (((kt - KTR) * 32 + gid) << 10) + lane * 16) = f;
        }
    if (t < DS) *(half_t*)(smem + HBUF_OFF + t * 2) = (half_t)0.f;  // h_{-1}=0
    __syncthreads();

    // q==0 lane c owns outputs n0w + nt*16 + c -> loads its own pre values
    const half_t* pp = pre + (size_t)b * LEN * DS + n0w + c;
    half_t* hsb = hs + (size_t)b * DS;

    float pv_cur[4] = {0.f, 0.f, 0.f, 0.f};
    if (q == 0) {
#pragma unroll
        for (int nt = 0; nt < 4; ++nt) pv_cur[nt] = (float)pp[nt * 16];
    }

    int par = 0;
    for (int l = 0; l < LEN; ++l) {
        const int ln = (l + 1 < LEN) ? (l + 1) : (LEN - 1);
        float pv_nxt[4];
        if (q == 0) {
#pragma unroll
            for (int nt = 0; nt < 4; ++nt)
                pv_nxt[nt] = (float)pp[(size_t)ln * DS + nt * 16];
        }

        const char* hbp = smem + HBUF_OFF + par * 1024;
        f32x4 acc0 = {0.f,0.f,0.f,0.f}, acc1 = {0.f,0.f,0.f,0.f};
        f32x4 acc2 = {0.f,0.f,0.f,0.f}, acc3 = {0.f,0.f,0.f,0.f};
#pragma unroll
        for (int kt = 0; kt < KTR; ++kt) {
            half8_t a = *(const half8_t*)(hbp + kt * 64 + q * 16);  // multicast
            acc0 = __builtin_amdgcn_mfma_f32_16x16x32_f16(a, breg[kt][0], acc0, 0, 0, 0);
            acc1 = __builtin_amdgcn_mfma_f32_16x16x32_f16(a, breg[kt][1], acc1, 0, 0, 0);
            acc2 = __builtin_amdgcn_mfma_f32_16x16x32_f16(a, breg[kt][2], acc2, 0, 0, 0);
            acc3 = __builtin_amdgcn_mfma_f32_16x16x32_f16(a, breg[kt][3], acc3, 0, 0, 0);
        }
#pragma unroll
        for (int kt = KTR; kt < NKT; ++kt) {
            half8_t a = *(const half8_t*)(hbp + kt * 64 + q * 16);
            const char* bb = smem + (((kt - KTR) * 32 + w * 4) << 10) + lane * 16;
            half8_t b0 = *(const half8_t*)(bb);
            half8_t b1 = *(const half8_t*)(bb + 1024);
            half8_t b2 = *(const half8_t*)(bb + 2048);
            half8_t b3 = *(const half8_t*)(bb + 3072);
            acc0 = __builtin_amdgcn_mfma_f32_16x16x32_f16(a, b0, acc0, 0, 0, 0);
            acc1 = __builtin_amdgcn_mfma_f32_16x16x32_f16(a, b1, acc1, 0, 0, 0);
            acc2 = __builtin_amdgcn_mfma_f32_16x16x32_f16(a, b2, acc2, 0, 0, 0);
            acc3 = __builtin_amdgcn_mfma_f32_16x16x32_f16(a, b3, acc3, 0, 0, 0);
        }

        if (q == 0) {  // C/D: col=lane&15, row=(lane>>4)*4+reg; m=0 -> q==0, .x
            half_t h0 = (half_t)fast_tanh(pv_cur[0] + acc0.x);
            half_t h1 = (half_t)fast_tanh(pv_cur[1] + acc1.x);
            half_t h2 = (half_t)fast_tanh(pv_cur[2] + acc2.x);
            half_t h3 = (half_t)fast_tanh(pv_cur[3] + acc3.x);
            char* hn = smem + HBUF_OFF + (par ^ 1) * 1024;
            *(half_t*)(hn + (n0w +  0 + c) * 2) = h0;
            *(half_t*)(hn + (n0w + 16 + c) * 2) = h1;
            *(half_t*)(hn + (n0w + 32 + c) * 2) = h2;
            *(half_t*)(hn + (n0w + 48 + c) * 2) = h3;
            half_t* hrow = hsb + (size_t)l * (B_ * DS);            // hs[(l*B+b)*DS]
            hrow[n0w +  0 + c] = h0;
            hrow[n0w + 16 + c] = h1;
            hrow[n0w + 32 + c] = h2;
            hrow[n0w + 48 + c] = h3;
        }
#pragma unroll
        for (int nt = 0; nt < 4; ++nt) pv_cur[nt] = pv_nxt[nt];
        par ^= 1;
        __syncthreads();
    }
}

// ---------------------------------------------------------------- kernel C
// y[r][o] = tanh(sum_s hs[r][s]*W_fc[o][s] + b_fc[o]),  r = l*B+b
__global__ __launch_bounds__(256) void rnn_out_kernel(
    const half_t* __restrict__ hs, const float* __restrict__ Wfc,
    const float* __restrict__ bfc, float* __restrict__ y)
{
    __shared__ half_t Hs[64 * 72];
    __shared__ half_t Ws[128 * 72];
    const int t  = threadIdx.x;
    const int r0 = blockIdx.x * 64;

    const int lb = (t >> 4) * 4;
    const int ob = (t & 15) * 8;
    float acc[4][8];
#pragma unroll
    for (int i = 0; i < 4; ++i)
#pragma unroll
        for (int j = 0; j < 8; ++j) acc[i][j] = 0.f;

    for (int kc = 0; kc < DS; kc += 64) {
#pragma unroll
        for (int i = 0; i < 2; ++i) {
            int u = i * 256 + t;
            int r = u >> 3, c8 = u & 7;
            uint4 v = ((const uint4*)(hs + (size_t)(r0 + r) * DS + kc))[c8];
            *(uint4*)&Hs[r * 72 + c8 * 8] = v;
        }
#pragma unroll
        for (int i = 0; i < 8; ++i) {
            int u = i * 256 + t;
            int o = u >> 4, c4 = u & 15;
            float4 wv = *(const float4*)&Wfc[(size_t)o * DS + kc + c4 * 4];
            half4_t hw = {(half_t)wv.x, (half_t)wv.y, (half_t)wv.z, (half_t)wv.w};
            *(half4_t*)&Ws[o * 72 + c4 * 4] = hw;
        }
        __syncthreads();
#pragma unroll
        for (int k8 = 0; k8 < 64; k8 += 8) {
            uint4 xa[4], wb[8];
#pragma unroll
            for (int i = 0; i < 4; ++i) xa[i] = *(const uint4*)&Hs[(lb + i) * 72 + k8];
#pragma unroll
            for (int j = 0; j < 8; ++j) wb[j] = *(const uint4*)&Ws[(ob + j) * 72 + k8];
#pragma unroll
            for (int i = 0; i < 4; ++i)
#pragma unroll
                for (int j = 0; j < 8; ++j) {
                    float a = acc[i][j];
                    a = fd2(xa[i].x, wb[j].x, a);
                    a = fd2(xa[i].y, wb[j].y, a);
                    a = fd2(xa[i].z, wb[j].z, a);
                    a = fd2(xa[i].w, wb[j].w, a);
                    acc[i][j] = a;
                }
        }
        __syncthreads();
    }

#pragma unroll
    for (int i = 0; i < 4; ++i) {
        float4 r0v = {fast_tanh(acc[i][0] + bfc[ob + 0]), fast_tanh(acc[i][1] + bfc[ob + 1]),
                      fast_tanh(acc[i][2] + bfc[ob + 2]), fast_tanh(acc[i][3] + bfc[ob + 3])};
        float4 r1v = {fast_tanh(acc[i][4] + bfc[ob + 4]), fast_tanh(acc[i][5] + bfc[ob + 5]),
                      fast_tanh(acc[i][6] + bfc[ob + 6]), fast_tanh(acc[i][7] + bfc[ob + 7])};
        float* yr = y + (size_t)(r0 + lb + i) * DIN + ob;
        *(float4*)yr       = r0v;
        *((float4*)yr + 1) = r1v;
    }
}

// ---------------------------------------------------------------- launch
extern "C" void kernel_launch(void* const* d_in, const int* in_sizes, int n_in,
                              void* d_out, int out_size, void* d_ws, size_t ws_size,
                              hipStream_t stream) {
    (void)in_sizes; (void)n_in; (void)out_size; (void)ws_size;
    const float* x   = (const float*)d_in[0];
    const float* Wih = (const float*)d_in[1];
    const float* Whh = (const float*)d_in[2];
    const float* bih = (const float*)d_in[3];
    const float* bhh = (const float*)d_in[4];
    const float* Wfc = (const float*)d_in[5];
    const float* bfc = (const float*)d_in[6];
    float* y = (float*)d_out;

    half_t* pre = (half_t*)d_ws;                                        // pre[b][l][h]: 64 MB
    half_t* hs  = (half_t*)((char*)d_ws + (size_t)B_ * LEN * DS * 2);   // hs[(l*B+b)][s]: 64 MB

    hipFuncSetAttribute((const void*)rnn_recur_kernel,
                        hipFuncAttributeMaxDynamicSharedMemorySize, LDS_BYTES);

    rnn_pre_kernel<<<dim3(LEN / 64, B_, DS / 128), 256, 0, stream>>>(x, Wih, bih, bhh, pre);
    rnn_recur_kernel<<<dim3(B_), 512, LDS_BYTES, stream>>>(Whh, pre, hs);
    rnn_out_kernel<<<dim3(LEN * B_ / 64), 256, 0, stream>>>(hs, Wfc, bfc, y);
}

// Round 6
// 3923.477 us; speedup vs baseline: 2.1238x; 1.2512x over previous
//
#include <hip/hip_runtime.h>
#include <cstdint>

typedef _Float16 half_t;
typedef __attribute__((ext_vector_type(2))) _Float16 half2_t;
typedef __attribute__((ext_vector_type(4))) _Float16 half4_t;
typedef __attribute__((ext_vector_type(8))) _Float16 half8_t;
typedef __attribute__((ext_vector_type(4))) float f32x4;

#define B_    32
#define DIN   128
#define LEN   2048
#define DS    512
#define NKT   16                            // K-tiles of 32 (16x16x32 MFMA)
#define KTR   12                            // K-tiles resident in regs/AGPRs (192 regs; 13 spills!)
#define KTL   (NKT - KTR)                   // 4 K-tiles streamed from LDS
#define LDSB_BYTES (KTL * 32 * 1024)        // 131072
#define HBUF_OFF   LDSB_BYTES
#define LDS_BYTES  (LDSB_BYTES + 2 * DS * 2)   // 133120 < 160 KiB

__device__ __forceinline__ float fast_tanh(float x) {
    float e = __expf(2.0f * x);        // large |x| saturates correctly via inf/0
    return 1.0f - 2.0f / (e + 1.0f);
}

// Barrier that drains only LDS (lgkmcnt), NOT outstanding global loads/stores
// (vmcnt). __syncthreads would emit s_waitcnt vmcnt(0) and serialize on the
// hs stores + pre prefetch every step (~300-500 cyc exposed L2 latency).
__device__ __forceinline__ void lds_barrier() {
    asm volatile("s_waitcnt lgkmcnt(0)\n\ts_barrier" ::: "memory");
}

__device__ __forceinline__ float fd2(uint32_t a, uint32_t b, float c) {
    return __builtin_amdgcn_fdot2(__builtin_bit_cast(half2_t, a),
                                  __builtin_bit_cast(half2_t, b), c, false);
}

// B-fragment for 16x16x32: lane(c=lane&15, q=lane>>4) holds B[k0+q*8+j][n0+c]
// = W[n0+c][k0+q*8+j], j=0..7 -> 8 consecutive f32 from W row n0+c.
__device__ __forceinline__ half8_t load_wfrag(const float* __restrict__ W,
                                              int n0, int c, int q, int kt) {
    const float* p = W + (size_t)(n0 + c) * DS + kt * 32 + q * 8;
    float4 f0 = *(const float4*)p;
    float4 f1 = *(const float4*)(p + 4);
    half8_t r = {(half_t)f0.x, (half_t)f0.y, (half_t)f0.z, (half_t)f0.w,
                 (half_t)f1.x, (half_t)f1.y, (half_t)f1.z, (half_t)f1.w};
    return r;
}

// ---------------------------------------------------------------- kernel A
// pre[b][l][h] = sum_d x[b][d][l]*W_ih[h][d] + b_ih[h] + b_hh[h]   (f16 out)
__global__ __launch_bounds__(256) void rnn_pre_kernel(
    const float* __restrict__ x, const float* __restrict__ Wih,
    const float* __restrict__ bih, const float* __restrict__ bhh,
    half_t* __restrict__ pre)
{
    __shared__ half_t Xs[64 * 136];
    __shared__ half_t Ws[128 * 136];
    const int t  = threadIdx.x;
    const int l0 = blockIdx.x * 64;
    const int b  = blockIdx.y;
    const int h0 = blockIdx.z * 128;

#pragma unroll
    for (int i = 0; i < 32; ++i) {
        int idx = i * 256 + t;
        int j = idx & 63, d = idx >> 6;
        Xs[j * 136 + d] = (half_t)x[(size_t)b * DIN * LEN + (size_t)d * LEN + l0 + j];
    }
#pragma unroll
    for (int i = 0; i < 16; ++i) {
        int f4 = i * 256 + t;
        int h = f4 >> 5, d4 = f4 & 31;
        float4 w = *(const float4*)&Wih[(size_t)(h0 + h) * DIN + d4 * 4];
        half4_t hw = {(half_t)w.x, (half_t)w.y, (half_t)w.z, (half_t)w.w};
        *(half4_t*)&Ws[h * 136 + d4 * 4] = hw;
    }
    __syncthreads();

    const int lb = (t >> 4) * 4;
    const int hb = (t & 15) * 8;
    float acc[4][8];
#pragma unroll
    for (int i = 0; i < 4; ++i)
#pragma unroll
        for (int j = 0; j < 8; ++j) acc[i][j] = 0.f;

    for (int kc = 0; kc < DIN; kc += 8) {
        uint4 xa[4], wb[8];
#pragma unroll
        for (int i = 0; i < 4; ++i) xa[i] = *(const uint4*)&Xs[(lb + i) * 136 + kc];
#pragma unroll
        for (int j = 0; j < 8; ++j) wb[j] = *(const uint4*)&Ws[(hb + j) * 136 + kc];
#pragma unroll
        for (int i = 0; i < 4; ++i)
#pragma unroll
            for (int j = 0; j < 8; ++j) {
                float a = acc[i][j];
                a = fd2(xa[i].x, wb[j].x, a);
                a = fd2(xa[i].y, wb[j].y, a);
                a = fd2(xa[i].z, wb[j].z, a);
                a = fd2(xa[i].w, wb[j].w, a);
                acc[i][j] = a;
            }
    }

    float bias[8];
#pragma unroll
    for (int j = 0; j < 8; ++j) bias[j] = bih[h0 + hb + j] + bhh[h0 + hb + j];
#pragma unroll
    for (int i = 0; i < 4; ++i) {
        half8_t s;
#pragma unroll
        for (int j = 0; j < 8; ++j) s[j] = (half_t)(acc[i][j] + bias[j]);
        *(half8_t*)&pre[((size_t)b * LEN + l0 + lb + i) * DS + h0 + hb] = s;
    }
}

// ---------------------------------------------------------------- kernel B
// MFMA scan: one block per batch. Wave w owns outputs n in [w*64, w*64+64)
// as 4 16-wide N-tiles. kt 0..11 B-frags in regs/AGPRs; kt 12..15 from LDS.
// pre values loaded directly by q==0 lanes; step barrier drains LDS only.
__global__ __launch_bounds__(512) __attribute__((amdgpu_waves_per_eu(2, 2)))
void rnn_recur_kernel(
    const float* __restrict__ Whh, const half_t* __restrict__ pre,
    half_t* __restrict__ hs)
{
    extern __shared__ char smem[];
    const int t    = threadIdx.x;
    const int b    = blockIdx.x;
    const int w    = t >> 6;
    const int lane = t & 63;
    const int c    = lane & 15;
    const int q    = lane >> 4;
    const int n0w  = w * 64;

    half8_t breg[KTR][4];
#pragma unroll
    for (int kt = 0; kt < KTR; ++kt)
#pragma unroll
        for (int nt = 0; nt < 4; ++nt)
            breg[kt][nt] = load_wfrag(Whh, n0w + nt * 16, c, q, kt);

#pragma unroll
    for (int kt = KTR; kt < NKT; ++kt)
#pragma unroll
        for (int nt = 0; nt < 4; ++nt) {
            half8_t f = load_wfrag(Whh, n0w + nt * 16, c, q, kt);
            int gid = w * 4 + nt;
            *(half8_t*)(smem + (((kt - KTR) * 32 + gid) << 10) + lane * 16) = f;
        }
    if (t < DS) *(half_t*)(smem + HBUF_OFF + t * 2) = (half_t)0.f;  // h_{-1}=0
    __syncthreads();

    // q==0 lane c owns outputs n0w + nt*16 + c -> loads its own pre values
    const half_t* pp = pre + (size_t)b * LEN * DS + n0w + c;
    half_t* hsb = hs + (size_t)b * DS;

    float pv_cur[4] = {0.f, 0.f, 0.f, 0.f};
    if (q == 0) {
#pragma unroll
        for (int nt = 0; nt < 4; ++nt) pv_cur[nt] = (float)pp[nt * 16];
    }

    int par = 0;
    for (int l = 0; l < LEN; ++l) {
        const int ln = (l + 1 < LEN) ? (l + 1) : (LEN - 1);
        float pv_nxt[4];
        if (q == 0) {
#pragma unroll
            for (int nt = 0; nt < 4; ++nt)
                pv_nxt[nt] = (float)pp[(size_t)ln * DS + nt * 16];
        }

        const char* hbp = smem + HBUF_OFF + par * 1024;
        f32x4 acc0 = {0.f,0.f,0.f,0.f}, acc1 = {0.f,0.f,0.f,0.f};
        f32x4 acc2 = {0.f,0.f,0.f,0.f}, acc3 = {0.f,0.f,0.f,0.f};
#pragma unroll
        for (int kt = 0; kt < KTR; ++kt) {
            half8_t a = *(const half8_t*)(hbp + kt * 64 + q * 16);  // multicast
            acc0 = __builtin_amdgcn_mfma_f32_16x16x32_f16(a, breg[kt][0], acc0, 0, 0, 0);
            acc1 = __builtin_amdgcn_mfma_f32_16x16x32_f16(a, breg[kt][1], acc1, 0, 0, 0);
            acc2 = __builtin_amdgcn_mfma_f32_16x16x32_f16(a, breg[kt][2], acc2, 0, 0, 0);
            acc3 = __builtin_amdgcn_mfma_f32_16x16x32_f16(a, breg[kt][3], acc3, 0, 0, 0);
        }
#pragma unroll
        for (int kt = KTR; kt < NKT; ++kt) {
            half8_t a = *(const half8_t*)(hbp + kt * 64 + q * 16);
            const char* bb = smem + (((kt - KTR) * 32 + w * 4) << 10) + lane * 16;
            half8_t b0 = *(const half8_t*)(bb);
            half8_t b1 = *(const half8_t*)(bb + 1024);
            half8_t b2 = *(const half8_t*)(bb + 2048);
            half8_t b3 = *(const half8_t*)(bb + 3072);
            acc0 = __builtin_amdgcn_mfma_f32_16x16x32_f16(a, b0, acc0, 0, 0, 0);
            acc1 = __builtin_amdgcn_mfma_f32_16x16x32_f16(a, b1, acc1, 0, 0, 0);
            acc2 = __builtin_amdgcn_mfma_f32_16x16x32_f16(a, b2, acc2, 0, 0, 0);
            acc3 = __builtin_amdgcn_mfma_f32_16x16x32_f16(a, b3, acc3, 0, 0, 0);
        }

        if (q == 0) {  // C/D: col=lane&15, row=(lane>>4)*4+reg; m=0 -> q==0, .x
            half_t h0 = (half_t)fast_tanh(pv_cur[0] + acc0.x);
            half_t h1 = (half_t)fast_tanh(pv_cur[1] + acc1.x);
            half_t h2 = (half_t)fast_tanh(pv_cur[2] + acc2.x);
            half_t h3 = (half_t)fast_tanh(pv_cur[3] + acc3.x);
            char* hn = smem + HBUF_OFF + (par ^ 1) * 1024;
            *(half_t*)(hn + (n0w +  0 + c) * 2) = h0;
            *(half_t*)(hn + (n0w + 16 + c) * 2) = h1;
            *(half_t*)(hn + (n0w + 32 + c) * 2) = h2;
            *(half_t*)(hn + (n0w + 48 + c) * 2) = h3;
            half_t* hrow = hsb + (size_t)l * (B_ * DS);            // hs[(l*B+b)*DS]
            hrow[n0w +  0 + c] = h0;
            hrow[n0w + 16 + c] = h1;
            hrow[n0w + 32 + c] = h2;
            hrow[n0w + 48 + c] = h3;
        }
#pragma unroll
        for (int nt = 0; nt < 4; ++nt) pv_cur[nt] = pv_nxt[nt];
        par ^= 1;
        lds_barrier();                 // LDS-only drain; global ops stay in flight
    }
}

// ---------------------------------------------------------------- kernel C
// y[r][o] = tanh(sum_s hs[r][s]*W_fc[o][s] + b_fc[o]),  r = l*B+b
__global__ __launch_bounds__(256) void rnn_out_kernel(
    const half_t* __restrict__ hs, const float* __restrict__ Wfc,
    const float* __restrict__ bfc, float* __restrict__ y)
{
    __shared__ half_t Hs[64 * 72];
    __shared__ half_t Ws[128 * 72];
    const int t  = threadIdx.x;
    const int r0 = blockIdx.x * 64;

    const int lb = (t >> 4) * 4;
    const int ob = (t & 15) * 8;
    float acc[4][8];
#pragma unroll
    for (int i = 0; i < 4; ++i)
#pragma unroll
        for (int j = 0; j < 8; ++j) acc[i][j] = 0.f;

    for (int kc = 0; kc < DS; kc += 64) {
#pragma unroll
        for (int i = 0; i < 2; ++i) {
            int u = i * 256 + t;
            int r = u >> 3, c8 = u & 7;
            uint4 v = ((const uint4*)(hs + (size_t)(r0 + r) * DS + kc))[c8];
            *(uint4*)&Hs[r * 72 + c8 * 8] = v;
        }
#pragma unroll
        for (int i = 0; i < 8; ++i) {
            int u = i * 256 + t;
            int o = u >> 4, c4 = u & 15;
            float4 wv = *(const float4*)&Wfc[(size_t)o * DS + kc + c4 * 4];
            half4_t hw = {(half_t)wv.x, (half_t)wv.y, (half_t)wv.z, (half_t)wv.w};
            *(half4_t*)&Ws[o * 72 + c4 * 4] = hw;
        }
        __syncthreads();
#pragma unroll
        for (int k8 = 0; k8 < 64; k8 += 8) {
            uint4 xa[4], wb[8];
#pragma unroll
            for (int i = 0; i < 4; ++i) xa[i] = *(const uint4*)&Hs[(lb + i) * 72 + k8];
#pragma unroll
            for (int j = 0; j < 8; ++j) wb[j] = *(const uint4*)&Ws[(ob + j) * 72 + k8];
#pragma unroll
            for (int i = 0; i < 4; ++i)
#pragma unroll
                for (int j = 0; j < 8; ++j) {
                    float a = acc[i][j];
                    a = fd2(xa[i].x, wb[j].x, a);
                    a = fd2(xa[i].y, wb[j].y, a);
                    a = fd2(xa[i].z, wb[j].z, a);
                    a = fd2(xa[i].w, wb[j].w, a);
                    acc[i][j] = a;
                }
        }
        __syncthreads();
    }

#pragma unroll
    for (int i = 0; i < 4; ++i) {
        float4 r0v = {fast_tanh(acc[i][0] + bfc[ob + 0]), fast_tanh(acc[i][1] + bfc[ob + 1]),
                      fast_tanh(acc[i][2] + bfc[ob + 2]), fast_tanh(acc[i][3] + bfc[ob + 3])};
        float4 r1v = {fast_tanh(acc[i][4] + bfc[ob + 4]), fast_tanh(acc[i][5] + bfc[ob + 5]),
                      fast_tanh(acc[i][6] + bfc[ob + 6]), fast_tanh(acc[i][7] + bfc[ob + 7])};
        float* yr = y + (size_t)(r0 + lb + i) * DIN + ob;
        *(float4*)yr       = r0v;
        *((float4*)yr + 1) = r1v;
    }
}

// ---------------------------------------------------------------- launch
extern "C" void kernel_launch(void* const* d_in, const int* in_sizes, int n_in,
                              void* d_out, int out_size, void* d_ws, size_t ws_size,
                              hipStream_t stream) {
    (void)in_sizes; (void)n_in; (void)out_size; (void)ws_size;
    const float* x   = (const float*)d_in[0];
    const float* Wih = (const float*)d_in[1];
    const float* Whh = (const float*)d_in[2];
    const float* bih = (const float*)d_in[3];
    const float* bhh = (const float*)d_in[4];
    const float* Wfc = (const float*)d_in[5];
    const float* bfc = (const float*)d_in[6];
    float* y = (float*)d_out;

    half_t* pre = (half_t*)d_ws;                                        // pre[b][l][h]: 64 MB
    half_t* hs  = (half_t*)((char*)d_ws + (size_t)B_ * LEN * DS * 2);   // hs[(l*B+b)][s]: 64 MB

    hipFuncSetAttribute((const void*)rnn_recur_kernel,
                        hipFuncAttributeMaxDynamicSharedMemorySize, LDS_BYTES);

    rnn_pre_kernel<<<dim3(LEN / 64, B_, DS / 128), 256, 0, stream>>>(x, Wih, bih, bhh, pre);
    rnn_recur_kernel<<<dim3(B_), 512, LDS_BYTES, stream>>>(Whh, pre, hs);
    rnn_out_kernel<<<dim3(LEN * B_ / 64), 256, 0, stream>>>(hs, Wfc, bfc, y);
}